// Round 1
// baseline (266.443 us; speedup 1.0000x reference)
//
#include <hip/hip_runtime.h>

// Problem constants (match reference)
#define N_PTS 32768
#define E_EDGES 524288
#define ROWS_PER_BLOCK 256
#define JCHUNK 4096
#define NROWBLK (N_PTS / ROWS_PER_BLOCK)   // 128
#define NJBLK (N_PTS / JCHUNK)             // 8

// ws layout: ws[0] = acc_r (double), ws[1] = acc_a (double)

__global__ void init_acc_kernel(double* ws) {
    ws[0] = 0.0;
    ws[1] = 0.0;
}

__global__ __launch_bounds__(256) void attract_kernel(
    const float* __restrict__ emb,
    const float* __restrict__ sparse,
    const int* __restrict__ heads,
    const int* __restrict__ tails,
    double* __restrict__ acc) {
    int tid = blockIdx.x * blockDim.x + threadIdx.x;
    int stride = gridDim.x * blockDim.x;
    float local = 0.0f;
    for (int e = tid; e < E_EDGES; e += stride) {
        int h = heads[e], t = tails[e];
        float2 eh = *reinterpret_cast<const float2*>(emb + 2 * h);
        float2 et = *reinterpret_cast<const float2*>(emb + 2 * t);
        float dx = eh.x - et.x;
        float dy = eh.y - et.y;
        float sqd = fmaf(dx, dx, dy * dy);
        // log(low_sim_pos) = -ln(1+sqd); accumulate sparse*log2(1+sqd) (positive)
        local = fmaf(sparse[e], __log2f(1.0f + sqd), local);
    }
    // wave64 reduce
    for (int off = 32; off; off >>= 1) local += __shfl_down(local, off, 64);
    if ((threadIdx.x & 63) == 0) atomicAdd(&acc[1], (double)local);
}

// Repulsive: each block = 256 rows x one 4096-wide j-chunk.
// S_i = sum_j [ log2(s*(1+eps)+eps) - log2(1+s) ],  s = min(sqd, 9999)
// contribution to acc_r: d_i * S_i   (log2 units; scaled in finalize)
__global__ __launch_bounds__(256) void repulse_kernel(
    const float* __restrict__ emb,
    const float* __restrict__ deg,
    double* __restrict__ acc) {
    __shared__ float2 jemb[JCHUNK];

    int rb = blockIdx.x % NROWBLK;
    int jc = blockIdx.x / NROWBLK;
    int j0 = jc * JCHUNK;

    // cooperative staging: 4096 float2 = 2048 float4
    const float4* src = reinterpret_cast<const float4*>(emb + 2 * j0);
    float4* dst = reinterpret_cast<float4*>(jemb);
    #pragma unroll
    for (int k = 0; k < JCHUNK / 2 / 256; ++k)
        dst[threadIdx.x + k * 256] = src[threadIdx.x + k * 256];
    __syncthreads();

    int i = rb * ROWS_PER_BLOCK + threadIdx.x;
    float xi = emb[2 * i + 0];
    float yi = emb[2 * i + 1];

    float S = 0.0f;
    for (int jg = 0; jg < JCHUNK; jg += 8) {
        float pa = 1.0f, pb = 1.0f;
        #pragma unroll
        for (int k = 0; k < 8; ++k) {
            float2 ej = jemb[jg + k];   // uniform address -> LDS broadcast
            float dx = xi - ej.x;
            float dy = yi - ej.y;
            float s = fmaf(dx, dx, dy * dy);
            s = fminf(s, 9999.0f);               // exact clamp: a==b==10000 at s=9999
            pa *= fmaf(s, 1.0001f, 1e-4f);       // s*(1+eps)+eps
            pb *= (1.0f + s);
        }
        S += __log2f(pa) - __log2f(pb);          // per-group diff: no cancellation blowup
    }

    float contrib = deg[i] * S;
    for (int off = 32; off; off >>= 1) contrib += __shfl_down(contrib, off, 64);
    if ((threadIdx.x & 63) == 0) atomicAdd(&acc[0], (double)contrib);
}

__global__ void finalize_kernel(const double* __restrict__ acc, float* __restrict__ out) {
    const double LN2 = 0.6931471805599453;
    double acc_r = acc[0];  // sum_i d_i * S_i  (log2 units)
    double acc_a = acc[1];  // sum_e sparse*log2(1+sqd)  (positive)
    // out = -loss_a - loss_r
    //     = ln2*acc_a - (2*NSR/(2N)) * ln2 * acc_r
    double loss = LN2 * (acc_a - (10.0 / 65536.0) * acc_r);
    out[0] = (float)loss;
}

extern "C" void kernel_launch(void* const* d_in, const int* in_sizes, int n_in,
                              void* d_out, int out_size, void* d_ws, size_t ws_size,
                              hipStream_t stream) {
    const float* emb    = (const float*)d_in[0];
    const float* sparse = (const float*)d_in[1];
    const float* deg    = (const float*)d_in[2];
    const int*   heads  = (const int*)d_in[3];
    const int*   tails  = (const int*)d_in[4];
    float* out = (float*)d_out;
    double* ws = (double*)d_ws;

    hipLaunchKernelGGL(init_acc_kernel, dim3(1), dim3(1), 0, stream, ws);
    hipLaunchKernelGGL(attract_kernel, dim3(512), dim3(256), 0, stream,
                       emb, sparse, heads, tails, ws);
    hipLaunchKernelGGL(repulse_kernel, dim3(NROWBLK * NJBLK), dim3(256), 0, stream,
                       emb, deg, ws);
    hipLaunchKernelGGL(finalize_kernel, dim3(1), dim3(1), 0, stream, ws, out);
}

// Round 2
// 225.215 us; speedup vs baseline: 1.1831x; 1.1831x over previous
//
#include <hip/hip_runtime.h>

// Problem constants (match reference)
#define N_PTS 32768
#define E_EDGES 524288
#define THREADS 256
#define ROWS_PER_THREAD 2
#define ROWS_PER_BLOCK (THREADS * ROWS_PER_THREAD)   // 512
#define JCHUNK 2048
#define NRB (N_PTS / ROWS_PER_BLOCK)   // 64
#define NJB (N_PTS / JCHUNK)           // 16

// ws layout: ws[0] = acc_r (double), ws[1] = acc_a (double)

__global__ void init_acc_kernel(double* ws) {
    ws[0] = 0.0;
    ws[1] = 0.0;
}

__global__ __launch_bounds__(256) void attract_kernel(
    const float* __restrict__ emb,
    const float* __restrict__ sparse,
    const int* __restrict__ heads,
    const int* __restrict__ tails,
    double* __restrict__ acc) {
    int tid = blockIdx.x * blockDim.x + threadIdx.x;
    int stride = gridDim.x * blockDim.x;
    float local = 0.0f;
    for (int e = tid; e < E_EDGES; e += stride) {
        int h = heads[e], t = tails[e];
        float2 eh = *reinterpret_cast<const float2*>(emb + 2 * h);
        float2 et = *reinterpret_cast<const float2*>(emb + 2 * t);
        float dx = eh.x - et.x;
        float dy = eh.y - et.y;
        float sqd = fmaf(dx, dx, dy * dy);
        // log(low_sim_pos) = -ln(1+sqd); accumulate sparse*log2(1+sqd) (positive)
        local = fmaf(sparse[e], __log2f(1.0f + sqd), local);
    }
    for (int off = 32; off; off >>= 1) local += __shfl_down(local, off, 64);
    if ((threadIdx.x & 63) == 0) atomicAdd(&acc[1], (double)local);
}

// Repulsive term.
// Per pair: b = 1+s computed via dot-form:
//   b = fma(-2x_i, x_j, fma(-2y_i, y_j, r_i + (r_j+1)))   [3 ops]
//   b = fmax(b, 1)    // exact-math b>=1; guards fp cancellation -> a<=0 -> NaN
//   a = fma(b, 1+eps, -1) == s*(1+eps)+eps                 [1 op]
//   pa *= a; pb *= b                                       [2 ops]
// Per 8-group: S += log2(pa) - log2(pb)  (products stay in f32 range:
//   high side 4000^8 ~ 6e28 < 3.4e38, low side 1e-4^8 = 1e-32 > min normal)
__global__ __launch_bounds__(256) void repulse_kernel(
    const float* __restrict__ emb,
    const float* __restrict__ deg,
    double* __restrict__ acc) {
    __shared__ float4 jt[JCHUNK];

    int rb = blockIdx.x % NRB;
    int jc = blockIdx.x / NRB;
    int j0 = jc * JCHUNK;

    // stage (x_j, y_j, r_j + 1, 0) -- coalesced float2 reads
    for (int k = threadIdx.x; k < JCHUNK; k += THREADS) {
        float2 p = *reinterpret_cast<const float2*>(emb + 2 * (j0 + k));
        float r1 = fmaf(p.x, p.x, p.y * p.y) + 1.0f;
        jt[k] = make_float4(p.x, p.y, r1, 0.0f);
    }
    __syncthreads();

    int i0 = rb * ROWS_PER_BLOCK + threadIdx.x;
    int i1 = i0 + THREADS;
    float2 p0 = *reinterpret_cast<const float2*>(emb + 2 * i0);
    float2 p1 = *reinterpret_cast<const float2*>(emb + 2 * i1);
    float X0 = -2.0f * p0.x, Y0 = -2.0f * p0.y, r0 = fmaf(p0.x, p0.x, p0.y * p0.y);
    float X1 = -2.0f * p1.x, Y1 = -2.0f * p1.y, r1 = fmaf(p1.x, p1.x, p1.y * p1.y);

    float S0 = 0.0f, S1 = 0.0f;
    for (int jg = 0; jg < JCHUNK; jg += 8) {
        float pa0 = 1.0f, pb0 = 1.0f, pa1 = 1.0f, pb1 = 1.0f;
        #pragma unroll
        for (int k = 0; k < 8; ++k) {
            float4 J = jt[jg + k];            // uniform addr -> LDS broadcast
            float b0 = fmaf(X0, J.x, fmaf(Y0, J.y, r0 + J.z));
            b0 = fmaxf(b0, 1.0f);
            float a0 = fmaf(b0, 1.0001f, -1.0f);
            pa0 *= a0; pb0 *= b0;
            float b1 = fmaf(X1, J.x, fmaf(Y1, J.y, r1 + J.z));
            b1 = fmaxf(b1, 1.0f);
            float a1 = fmaf(b1, 1.0001f, -1.0f);
            pa1 *= a1; pb1 *= b1;
        }
        S0 += __log2f(pa0) - __log2f(pb0);
        S1 += __log2f(pa1) - __log2f(pb1);
    }

    float contrib = deg[i0] * S0 + deg[i1] * S1;
    for (int off = 32; off; off >>= 1) contrib += __shfl_down(contrib, off, 64);
    if ((threadIdx.x & 63) == 0) atomicAdd(&acc[0], (double)contrib);
}

__global__ void finalize_kernel(const double* __restrict__ acc, float* __restrict__ out) {
    const double LN2 = 0.6931471805599453;
    double acc_r = acc[0];  // sum_i d_i * S_i  (log2 units)
    double acc_a = acc[1];  // sum_e sparse*log2(1+sqd)  (positive)
    double loss = LN2 * (acc_a - (10.0 / 65536.0) * acc_r);
    out[0] = (float)loss;
}

extern "C" void kernel_launch(void* const* d_in, const int* in_sizes, int n_in,
                              void* d_out, int out_size, void* d_ws, size_t ws_size,
                              hipStream_t stream) {
    const float* emb    = (const float*)d_in[0];
    const float* sparse = (const float*)d_in[1];
    const float* deg    = (const float*)d_in[2];
    const int*   heads  = (const int*)d_in[3];
    const int*   tails  = (const int*)d_in[4];
    float* out = (float*)d_out;
    double* ws = (double*)d_ws;

    hipLaunchKernelGGL(init_acc_kernel, dim3(1), dim3(1), 0, stream, ws);
    hipLaunchKernelGGL(attract_kernel, dim3(512), dim3(256), 0, stream,
                       emb, sparse, heads, tails, ws);
    hipLaunchKernelGGL(repulse_kernel, dim3(NRB * NJB), dim3(256), 0, stream,
                       emb, deg, ws);
    hipLaunchKernelGGL(finalize_kernel, dim3(1), dim3(1), 0, stream, ws, out);
}

// Round 3
// 212.489 us; speedup vs baseline: 1.2539x; 1.0599x over previous
//
#include <hip/hip_runtime.h>

// Problem constants (match reference)
#define N_PTS 32768
#define E_EDGES 524288
#define THREADS 256
#define ROWS_PER_THREAD 2
#define ROWS_PER_BLOCK (THREADS * ROWS_PER_THREAD)   // 512
#define JCHUNK 1024
#define NRB (N_PTS / ROWS_PER_BLOCK)   // 64
#define NJB (N_PTS / JCHUNK)           // 32  -> grid 2048 = 8 blocks/CU

// ws layout: ws[0] = acc_r (double), ws[1] = acc_a (double)

__global__ void init_acc_kernel(double* ws) {
    ws[0] = 0.0;
    ws[1] = 0.0;
}

__global__ __launch_bounds__(256) void attract_kernel(
    const float* __restrict__ emb,
    const float* __restrict__ sparse,
    const int* __restrict__ heads,
    const int* __restrict__ tails,
    double* __restrict__ acc) {
    int tid = blockIdx.x * blockDim.x + threadIdx.x;
    int stride = gridDim.x * blockDim.x;
    float local = 0.0f;
    for (int e = tid; e < E_EDGES; e += stride) {
        int h = heads[e], t = tails[e];
        float2 eh = *reinterpret_cast<const float2*>(emb + 2 * h);
        float2 et = *reinterpret_cast<const float2*>(emb + 2 * t);
        float dx = eh.x - et.x;
        float dy = eh.y - et.y;
        float sqd = fmaf(dx, dx, dy * dy);
        local = fmaf(sparse[e], __log2f(1.0f + sqd), local);
    }
    for (int off = 32; off; off >>= 1) local += __shfl_down(local, off, 64);
    if ((threadIdx.x & 63) == 0) atomicAdd(&acc[1], (double)local);
}

// Repulsive term, difference form (no LDS, no clamp needed):
//   b = 1 + dx^2 + dy^2   (all non-negative adds -> b >= 1 exact in fp)
//   a = fma(b, 1+eps, -1) = s*(1+eps)+eps
//   S_i += log2(prod a) - log2(prod b)  per 8-group
// J-points read with block-uniform indices (L2-resident, broadcast).
__global__ __launch_bounds__(256) void repulse_kernel(
    const float* __restrict__ emb,
    const float* __restrict__ deg,
    double* __restrict__ acc) {
    int rb = blockIdx.x % NRB;
    int jc = blockIdx.x / NRB;
    int j0 = jc * JCHUNK;

    int i0 = rb * ROWS_PER_BLOCK + threadIdx.x;
    int i1 = i0 + THREADS;
    float2 p0 = *reinterpret_cast<const float2*>(emb + 2 * i0);
    float2 p1 = *reinterpret_cast<const float2*>(emb + 2 * i1);
    float x0 = p0.x, y0 = p0.y, x1 = p1.x, y1 = p1.y;

    const float4* __restrict__ P4 = reinterpret_cast<const float4*>(emb);
    int q0 = j0 >> 1;   // float4 index of chunk start (2 points per float4)

    float S0 = 0.0f, S1 = 0.0f;

    for (int jg = 0; jg < JCHUNK; jg += 8) {
        int q = q0 + (jg >> 1);
        // 4 uniform 16B loads = 8 j-points, batched for latency hiding
        float4 A = P4[q + 0];
        float4 B = P4[q + 1];
        float4 C = P4[q + 2];
        float4 D = P4[q + 3];

        float pa0 = 1.0f, pb0 = 1.0f, pa1 = 1.0f, pb1 = 1.0f;

#define PAIR(px, py)                                              \
        {                                                         \
            float dx0 = x0 - (px), dy0 = y0 - (py);               \
            float b0 = fmaf(dx0, dx0, fmaf(dy0, dy0, 1.0f));      \
            float a0 = fmaf(b0, 1.0001f, -1.0f);                  \
            pa0 *= a0; pb0 *= b0;                                 \
            float dx1 = x1 - (px), dy1 = y1 - (py);               \
            float b1 = fmaf(dx1, dx1, fmaf(dy1, dy1, 1.0f));      \
            float a1 = fmaf(b1, 1.0001f, -1.0f);                  \
            pa1 *= a1; pb1 *= b1;                                 \
        }

        PAIR(A.x, A.y) PAIR(A.z, A.w)
        PAIR(B.x, B.y) PAIR(B.z, B.w)
        PAIR(C.x, C.y) PAIR(C.z, C.w)
        PAIR(D.x, D.y) PAIR(D.z, D.w)
#undef PAIR

        S0 += __log2f(pa0) - __log2f(pb0);
        S1 += __log2f(pa1) - __log2f(pb1);
    }

    float contrib = deg[i0] * S0 + deg[i1] * S1;
    for (int off = 32; off; off >>= 1) contrib += __shfl_down(contrib, off, 64);
    if ((threadIdx.x & 63) == 0) atomicAdd(&acc[0], (double)contrib);
}

__global__ void finalize_kernel(const double* __restrict__ acc, float* __restrict__ out) {
    const double LN2 = 0.6931471805599453;
    double acc_r = acc[0];  // sum_i d_i * S_i  (log2 units)
    double acc_a = acc[1];  // sum_e sparse*log2(1+sqd)
    double loss = LN2 * (acc_a - (10.0 / 65536.0) * acc_r);
    out[0] = (float)loss;
}

extern "C" void kernel_launch(void* const* d_in, const int* in_sizes, int n_in,
                              void* d_out, int out_size, void* d_ws, size_t ws_size,
                              hipStream_t stream) {
    const float* emb    = (const float*)d_in[0];
    const float* sparse = (const float*)d_in[1];
    const float* deg    = (const float*)d_in[2];
    const int*   heads  = (const int*)d_in[3];
    const int*   tails  = (const int*)d_in[4];
    float* out = (float*)d_out;
    double* ws = (double*)d_ws;

    hipLaunchKernelGGL(init_acc_kernel, dim3(1), dim3(1), 0, stream, ws);
    hipLaunchKernelGGL(attract_kernel, dim3(512), dim3(256), 0, stream,
                       emb, sparse, heads, tails, ws);
    hipLaunchKernelGGL(repulse_kernel, dim3(NRB * NJB), dim3(256), 0, stream,
                       emb, deg, ws);
    hipLaunchKernelGGL(finalize_kernel, dim3(1), dim3(1), 0, stream, ws, out);
}